// Round 1
// 340.529 us; speedup vs baseline: 1.1072x; 1.1072x over previous
//
#include <hip/hip_runtime.h>
#include <math.h>

#define B_ 64
#define P_ 25
#define D_ 128
#define T_ 120
#define L_ 2
#define K_ 4
#define GT 4                  // t-slices per block (2 waves each -> 8 waves/block)
#define LN_EPS 1e-5f
#define HSTRF 132             // fp32 LDS row stride: 16B-aligned, %32==4 -> <=2-way banks

typedef __attribute__((ext_vector_type(8))) _Float16 half8;  // MFMA A/B frag
typedef __attribute__((ext_vector_type(4))) float f4v;       // MFMA accumulator

// Pre-swizzle W[l][k][n] (fp32) into per-lane fp16 B-fragments:
// wf[(((l*8+nt)*4+ks)*64+lane)*8 + j] = f16( W[l][ks*32+(lane>>4)*8+j][nt*16+(lane&15)] )
__global__ __launch_bounds__(256) void pack_w(const float* __restrict__ W,
                                              _Float16* __restrict__ wf) {
    int id = blockIdx.x * 256 + threadIdx.x;          // 0..4095
    int lane = id & 63, rest = id >> 6;
    int ks = rest & 3, nt = (rest >> 2) & 7, l = rest >> 5;
    int n  = nt * 16 + (lane & 15);
    int kb = ks * 32 + (lane >> 4) * 8;
    _Float16 v[8];
    for (int j = 0; j < 8; ++j)
        v[j] = (_Float16)W[((size_t)l * D_ + kb + j) * D_ + n];
    *reinterpret_cast<half8*>(wf + (size_t)id * 8) = *reinterpret_cast<half8*>(v);
}

// One block per (b, 4 consecutive t); 8 waves: wave w owns t-slice w>>1,
// row-tile rt = w&1 (rows rt*16 .. rt*16+15). Row-split doubles waves per
// LDS byte (occupancy 12 -> 24 waves/CU) with zero duplicated arithmetic:
// mix, MFMA and the LN reduction are all row-tile-local. Numerics identical
// to the 1-wave/t version (same ops per row, same order).
// Grid is (b fastest, tg second): t-adjacent blocks differ by 64 in linear id
// == 0 mod 8 -> same XCD -> the 64B x/out lines (16 t's, 4 blocks) are L2-shared.
__global__ __launch_bounds__(512) void gcn_mfma(
    const float* __restrict__ x,       // [B,P,D,T]
    const float* __restrict__ dist,    // [B,T,P,P]
    const _Float16* __restrict__ wf,   // packed fp16 W fragments
    const float* __restrict__ biases,  // [L,D]
    const float* __restrict__ gamma,   // [L,D]
    const float* __restrict__ beta,    // [L,D]
    float* __restrict__ out)           // [B,P,D,T]
{
    const int b = blockIdx.x, tg = blockIdx.y;
    const int t0 = tg * GT;
    const int tid = threadIdx.x;
    const int wave = tid >> 6, lane = tid & 63;

    __shared__ __align__(16) float h_lds[GT][P_][HSTRF];  // fp32 h (52.8 KB)
    __shared__ unsigned char nbr[GT][P_][4];              // 400 B

    // ---- load x -> h fp32 (float4 across the 4 t's: 16B-dense) ----
    {
        const float* xb = x + (size_t)b * P_ * D_ * T_ + t0;
        for (int i = tid; i < P_ * D_; i += 512) {
            int p = i >> 7, d = i & 127;
            float4 v = *reinterpret_cast<const float4*>(xb + (size_t)i * T_);
            h_lds[0][p][d] = v.x;
            h_lds[1][p][d] = v.y;
            h_lds[2][p][d] = v.z;
            h_lds[3][p][d] = v.w;
        }
    }

    // ---- kNN from global dist (L2-hot). Row degree always K+1=5 -> adj = A/5.
    if (tid < GT * P_) {
        int tt = tid / P_, p = tid % P_;
        const float* drow = dist + (((size_t)b * T_ + t0 + tt) * P_ + p) * P_;
        float dr[P_];
        #pragma unroll
        for (int q = 0; q < P_; ++q) dr[q] = drow[q];
        dr[p] = 1e30f;
        unsigned chosen = 0;
        #pragma unroll
        for (int j = 0; j < K_; ++j) {
            float best = 1e29f; int bi = 0;
            #pragma unroll
            for (int q = 0; q < P_; ++q)   // strict < -> lowest index wins ties
                if (!((chosen >> q) & 1u) && dr[q] < best) { best = dr[q]; bi = q; }
            chosen |= 1u << bi;
            nbr[tt][p][j] = (unsigned char)bi;
        }
    }
    __syncthreads();

    const int t  = wave >> 1;          // t-slice owned by this wave-pair
    const int rt = wave & 1;           // row-tile: rows rt*16 .. rt*16+15
    const int m = lane & 15, quad = lane >> 4;
    const int row = rt * 16 + m;
    const bool vR = (row < P_);
    const int  pr = vR ? row : 0;
    const float sc = vR ? 0.2f : 0.0f;  // zero out padded rows 25..31
    const float* hb = &h_lds[t][0][0];
    const uchar4 nb = *reinterpret_cast<const uchar4*>(&nbr[t][pr][0]);
    const int n0 = nb.x, n1 = nb.y, n2 = nb.z, n3 = nb.w;

    for (int l = 0; l < L_; ++l) {
        f4v acc[8];
        #pragma unroll
        for (int nt = 0; nt < 8; ++nt)
            acc[nt] = (f4v){0.f, 0.f, 0.f, 0.f};
        const _Float16* wfl = wf + (size_t)l * 8 * 4 * 64 * 8;

        #pragma unroll
        for (int ks = 0; ks < 4; ++ks) {
            const int ko = ks * 32 + quad * 8;
            // ---- g = 0.2*(h[row] + sum of 4 nbr rows), exact fp32 ----
            float g[8];
            {
                const float* r  = hb + pr * HSTRF + ko;
                const float* p0 = hb + n0 * HSTRF + ko;
                const float* p1 = hb + n1 * HSTRF + ko;
                const float* p2 = hb + n2 * HSTRF + ko;
                const float* p3 = hb + n3 * HSTRF + ko;
                #pragma unroll
                for (int j = 0; j < 8; ++j)
                    g[j] = sc * (r[j] + p0[j] + p1[j] + p2[j] + p3[j]);
            }
            // ---- split-precision fp16 fragments: g ~= hi + lo (22-bit mantissa)
            half8 ahi, alo;
            #pragma unroll
            for (int j = 0; j < 8; ++j) {
                _Float16 h0 = (_Float16)g[j];
                ahi[j] = h0; alo[j] = (_Float16)(g[j] - (float)h0);
            }
            #pragma unroll
            for (int nt = 0; nt < 8; ++nt) {
                half8 bf = *reinterpret_cast<const half8*>(
                    wfl + (size_t)((nt * 4 + ks) * 64 + lane) * 8);  // coalesced, L2-hot
                acc[nt] = __builtin_amdgcn_mfma_f32_16x16x32_f16(ahi, bf, acc[nt], 0, 0, 0);
                acc[nt] = __builtin_amdgcn_mfma_f32_16x16x32_f16(alo, bf, acc[nt], 0, 0, 0);
            }
        }

        // Waves of a t-pair share h_lds[t]: all mix reads (above) must drain
        // before any epilogue residual write (below) -> WAR barrier.
        __syncthreads();

        // ---- epilogue in registers: bias + relu + LN + residual into h ----
        float bsv[8], gmv[8], btv[8];
        #pragma unroll
        for (int nt = 0; nt < 8; ++nt) {
            int c = l * D_ + nt * 16 + m;
            bsv[nt] = biases[c]; gmv[nt] = gamma[c]; btv[nt] = beta[c];
        }
        // C layout: col = nt*16 + (lane&15), row = rt*16 + quad*4 + r.
        // A row's 128 cols live in the 16 lanes of one quad -> xor 1,2,4,8.
        #pragma unroll
        for (int r = 0; r < 4; ++r) {
            const int mm = rt * 16 + quad * 4 + r;
            float z[8], s = 0.f, s2 = 0.f;
            #pragma unroll
            for (int nt = 0; nt < 8; ++nt) {
                float zz = fmaxf(acc[nt][r] + bsv[nt], 0.f);
                z[nt] = zz; s += zz; s2 += zz * zz;
            }
            #pragma unroll
            for (int o = 1; o < 16; o <<= 1) {   // reduce within quad (16 lanes)
                s  += __shfl_xor(s, o);
                s2 += __shfl_xor(s2, o);
            }
            if (mm < P_) {
                float mu  = s * (1.f / 128.f);
                float var = s2 * (1.f / 128.f) - mu * mu;
                float rs  = rsqrtf(var + LN_EPS);
                #pragma unroll
                for (int nt = 0; nt < 8; ++nt)
                    h_lds[t][mm][nt * 16 + m] += (z[nt] - mu) * rs * gmv[nt] + btv[nt];
            }
        }
        __syncthreads();   // h writes visible for next layer / store
    }

    // ---- store: out[b,p,d,t0..t0+3] as float4 ----
    {
        float* ob = out + (size_t)b * P_ * D_ * T_ + t0;
        for (int i = tid; i < P_ * D_; i += 512) {
            int p = i >> 7, d = i & 127;
            float4 v;
            v.x = h_lds[0][p][d];
            v.y = h_lds[1][p][d];
            v.z = h_lds[2][p][d];
            v.w = h_lds[3][p][d];
            *reinterpret_cast<float4*>(ob + (size_t)i * T_) = v;
        }
    }
}

extern "C" void kernel_launch(void* const* d_in, const int* in_sizes, int n_in,
                              void* d_out, int out_size, void* d_ws, size_t ws_size,
                              hipStream_t stream) {
    const float* x    = (const float*)d_in[0];
    const float* dist = (const float*)d_in[1];
    const float* w    = (const float*)d_in[2];
    const float* bias = (const float*)d_in[3];
    const float* gam  = (const float*)d_in[4];
    const float* bet  = (const float*)d_in[5];
    float* out = (float*)d_out;
    _Float16* wf = (_Float16*)d_ws;   // 2*8*4*64*8 fp16 = 64KB

    pack_w<<<16, 256, 0, stream>>>(w, wf);
    // b fastest in linear block id -> t-adjacent blocks (delta id = 64 == 0 mod 8)
    // land on the same XCD, sharing the 64B x/out lines in that XCD's L2.
    gcn_mfma<<<dim3(B_, T_ / GT), 512, 0, stream>>>(x, dist, wf, bias, gam, bet, out);
}

// Round 2
// 337.779 us; speedup vs baseline: 1.1162x; 1.0081x over previous
//
#include <hip/hip_runtime.h>
#include <math.h>

#define B_ 64
#define P_ 25
#define D_ 128
#define T_ 120
#define L_ 2
#define K_ 4
#define GT 4                  // t-slices per block (1 per wave -> 4 waves/block)
#define LN_EPS 1e-5f
#define HSTRF 132             // fp32 LDS row stride: 16B-aligned, %32==4 -> <=2-way banks

typedef __attribute__((ext_vector_type(8))) _Float16 half8;  // MFMA A/B frag
typedef __attribute__((ext_vector_type(4))) float f4v;       // MFMA accumulator

// Pre-swizzle W[l][k][n] (fp32) into per-lane fp16 B-fragments:
// wf[(((l*8+nt)*4+ks)*64+lane)*8 + j] = f16( W[l][ks*32+(lane>>4)*8+j][nt*16+(lane&15)] )
__global__ __launch_bounds__(256) void pack_w(const float* __restrict__ W,
                                              _Float16* __restrict__ wf) {
    int id = blockIdx.x * 256 + threadIdx.x;          // 0..4095
    int lane = id & 63, rest = id >> 6;
    int ks = rest & 3, nt = (rest >> 2) & 7, l = rest >> 5;
    int n  = nt * 16 + (lane & 15);
    int kb = ks * 32 + (lane >> 4) * 8;
    _Float16 v[8];
    for (int j = 0; j < 8; ++j)
        v[j] = (_Float16)W[((size_t)l * D_ + kb + j) * D_ + n];
    *reinterpret_cast<half8*>(wf + (size_t)id * 8) = *reinterpret_cast<half8*>(v);
}

// One block per (b, 4 consecutive t); wave w owns t-slice w ENTIRELY.
// h_lds[t] is wave-private for the whole main loop -> ZERO __syncthreads()
// between layers (same-wave LDS ordering = compiler lgkmcnt). This
// desynchronizes the 12 resident waves/CU so their LDS/MFMA/VALU phases
// hide each other's latency (round-1's barriers kept all waves in phase:
// occupancy doubled but every pipe stayed <20% busy).
// __launch_bounds__(256,3): VGPR cap ~170 -> deep load window for the mix.
// Grid is (b fastest, tg second): t-adjacent blocks differ by 64 in linear id
// == 0 mod 8 -> same XCD -> the 64B x/out lines (16 t's, 4 blocks) are L2-shared.
__global__ __launch_bounds__(256, 3) void gcn_mfma(
    const float* __restrict__ x,       // [B,P,D,T]
    const float* __restrict__ dist,    // [B,T,P,P]
    const _Float16* __restrict__ wf,   // packed fp16 W fragments
    const float* __restrict__ biases,  // [L,D]
    const float* __restrict__ gamma,   // [L,D]
    const float* __restrict__ beta,    // [L,D]
    float* __restrict__ out)           // [B,P,D,T]
{
    const int b = blockIdx.x, tg = blockIdx.y;
    const int t0 = tg * GT;
    const int tid = threadIdx.x;
    const int wave = tid >> 6, lane = tid & 63;

    __shared__ __align__(16) float h_lds[GT][P_][HSTRF];  // fp32 h (52.8 KB)
    __shared__ unsigned char nbr[GT][P_][4];              // 400 B

    // ---- kNN dist loads issued FIRST (deepest-latency path); the top-k
    //      selection is deferred until after the x-load so ~900cyc HBM
    //      latency hides under the staging issue.
    float dr[P_];
    const bool doknn = (tid < GT * P_);
    int tt = 0, pp = 0;
    if (doknn) {
        tt = tid / P_; pp = tid % P_;
        const float* drow = dist + (((size_t)b * T_ + t0 + tt) * P_ + pp) * P_;
        #pragma unroll
        for (int q = 0; q < P_; ++q) dr[q] = drow[q];
    }

    // ---- load x -> h fp32 (float4 across the 4 t's: 16B-dense) ----
    {
        const float* xb = x + (size_t)b * P_ * D_ * T_ + t0;
        for (int i = tid; i < P_ * D_; i += 256) {
            int p = i >> 7, d = i & 127;
            float4 v = *reinterpret_cast<const float4*>(xb + (size_t)i * T_);
            h_lds[0][p][d] = v.x;
            h_lds[1][p][d] = v.y;
            h_lds[2][p][d] = v.z;
            h_lds[3][p][d] = v.w;
        }
    }

    // ---- kNN selection. Row degree always K+1=5 -> adj = A/5.
    if (doknn) {
        dr[pp] = 1e30f;
        unsigned chosen = 0;
        #pragma unroll
        for (int j = 0; j < K_; ++j) {
            float best = 1e29f; int bi = 0;
            #pragma unroll
            for (int q = 0; q < P_; ++q)   // strict < -> lowest index wins ties
                if (!((chosen >> q) & 1u) && dr[q] < best) { best = dr[q]; bi = q; }
            chosen |= 1u << bi;
            nbr[tt][pp][j] = (unsigned char)bi;
        }
    }
    __syncthreads();   // h + nbr visible to all waves (x-load wrote all planes)

    const int t = wave;
    const int m = lane & 15, quad = lane >> 4;
    const int mB = m + 16;
    const bool vB = (mB < P_);
    const int  prB = vB ? mB : 0;
    const float scB = vB ? 0.2f : 0.0f;   // zero out padded rows 25..31
    const float* hb = &h_lds[t][0][0];
    const uchar4 nb0 = *reinterpret_cast<const uchar4*>(&nbr[t][m][0]);
    const uchar4 nb1 = *reinterpret_cast<const uchar4*>(&nbr[t][prB][0]);
    const int n00 = nb0.x, n01 = nb0.y, n02 = nb0.z, n03 = nb0.w;
    const int n10 = nb1.x, n11 = nb1.y, n12 = nb1.z, n13 = nb1.w;

    for (int l = 0; l < L_; ++l) {
        f4v acc[8][2];
        #pragma unroll
        for (int nt = 0; nt < 8; ++nt) {
            acc[nt][0] = (f4v){0.f, 0.f, 0.f, 0.f};
            acc[nt][1] = (f4v){0.f, 0.f, 0.f, 0.f};
        }
        const _Float16* wfl = wf + (size_t)l * 8 * 4 * 64 * 8;

        #pragma unroll
        for (int ks = 0; ks < 4; ++ks) {
            const int ko = ks * 32 + quad * 8;
            // ---- g = 0.2*(h[row] + sum of 4 nbr rows), exact fp32 ----
            float g0[8], g1[8];
            {
                const float* r  = hb + m   * HSTRF + ko;
                const float* p0 = hb + n00 * HSTRF + ko;
                const float* p1 = hb + n01 * HSTRF + ko;
                const float* p2 = hb + n02 * HSTRF + ko;
                const float* p3 = hb + n03 * HSTRF + ko;
                #pragma unroll
                for (int j = 0; j < 8; ++j)
                    g0[j] = 0.2f * (r[j] + p0[j] + p1[j] + p2[j] + p3[j]);
            }
            {
                const float* r  = hb + prB * HSTRF + ko;
                const float* p0 = hb + n10 * HSTRF + ko;
                const float* p1 = hb + n11 * HSTRF + ko;
                const float* p2 = hb + n12 * HSTRF + ko;
                const float* p3 = hb + n13 * HSTRF + ko;
                #pragma unroll
                for (int j = 0; j < 8; ++j)
                    g1[j] = scB * (r[j] + p0[j] + p1[j] + p2[j] + p3[j]);
            }
            // ---- split-precision fp16 fragments: g ~= hi + lo (22-bit mantissa)
            half8 ahi0, alo0, ahi1, alo1;
            #pragma unroll
            for (int j = 0; j < 8; ++j) {
                _Float16 h0 = (_Float16)g0[j];
                ahi0[j] = h0; alo0[j] = (_Float16)(g0[j] - (float)h0);
                _Float16 h1 = (_Float16)g1[j];
                ahi1[j] = h1; alo1[j] = (_Float16)(g1[j] - (float)h1);
            }
            #pragma unroll
            for (int nt = 0; nt < 8; ++nt) {
                half8 bf = *reinterpret_cast<const half8*>(
                    wfl + (size_t)((nt * 4 + ks) * 64 + lane) * 8);  // coalesced, L2-hot
                acc[nt][0] = __builtin_amdgcn_mfma_f32_16x16x32_f16(ahi0, bf, acc[nt][0], 0, 0, 0);
                acc[nt][0] = __builtin_amdgcn_mfma_f32_16x16x32_f16(alo0, bf, acc[nt][0], 0, 0, 0);
                acc[nt][1] = __builtin_amdgcn_mfma_f32_16x16x32_f16(ahi1, bf, acc[nt][1], 0, 0, 0);
                acc[nt][1] = __builtin_amdgcn_mfma_f32_16x16x32_f16(alo1, bf, acc[nt][1], 0, 0, 0);
            }
        }

        // ---- epilogue in registers: bias + relu + LN + residual into h ----
        // Wave-private h plane: NO barrier needed (same-wave lgkmcnt ordering).
        float bsv[8], gmv[8], btv[8];
        #pragma unroll
        for (int nt = 0; nt < 8; ++nt) {
            int c = l * D_ + nt * 16 + m;
            bsv[nt] = biases[c]; gmv[nt] = gamma[c]; btv[nt] = beta[c];
        }
        // C layout: col = nt*16 + (lane&15), row = mt*16 + quad*4 + r.
        // A row's 128 cols live in the 16 lanes of one quad -> xor 1,2,4,8.
        #pragma unroll
        for (int mt = 0; mt < 2; ++mt) {
            #pragma unroll
            for (int r = 0; r < 4; ++r) {
                const int mm = mt * 16 + quad * 4 + r;
                float z[8], s = 0.f, s2 = 0.f;
                #pragma unroll
                for (int nt = 0; nt < 8; ++nt) {
                    float zz = fmaxf(acc[nt][mt][r] + bsv[nt], 0.f);
                    z[nt] = zz; s += zz; s2 += zz * zz;
                }
                #pragma unroll
                for (int o = 1; o < 16; o <<= 1) {   // reduce within quad (16 lanes)
                    s  += __shfl_xor(s, o);
                    s2 += __shfl_xor(s2, o);
                }
                if (mm < P_) {
                    float mu  = s * (1.f / 128.f);
                    float var = s2 * (1.f / 128.f) - mu * mu;
                    float rs  = rsqrtf(var + LN_EPS);
                    #pragma unroll
                    for (int nt = 0; nt < 8; ++nt)
                        h_lds[t][mm][nt * 16 + m] += (z[nt] - mu) * rs * gmv[nt] + btv[nt];
                }
            }
        }
        // no __syncthreads(): next layer's mix reads only this wave's plane
    }

    __syncthreads();   // store reads all 4 planes cooperatively

    // ---- store: out[b,p,d,t0..t0+3] as float4 ----
    {
        float* ob = out + (size_t)b * P_ * D_ * T_ + t0;
        for (int i = tid; i < P_ * D_; i += 256) {
            int p = i >> 7, d = i & 127;
            float4 v;
            v.x = h_lds[0][p][d];
            v.y = h_lds[1][p][d];
            v.z = h_lds[2][p][d];
            v.w = h_lds[3][p][d];
            *reinterpret_cast<float4*>(ob + (size_t)i * T_) = v;
        }
    }
}

extern "C" void kernel_launch(void* const* d_in, const int* in_sizes, int n_in,
                              void* d_out, int out_size, void* d_ws, size_t ws_size,
                              hipStream_t stream) {
    const float* x    = (const float*)d_in[0];
    const float* dist = (const float*)d_in[1];
    const float* w    = (const float*)d_in[2];
    const float* bias = (const float*)d_in[3];
    const float* gam  = (const float*)d_in[4];
    const float* bet  = (const float*)d_in[5];
    float* out = (float*)d_out;
    _Float16* wf = (_Float16*)d_ws;   // 2*8*4*64*8 fp16 = 64KB

    pack_w<<<16, 256, 0, stream>>>(w, wf);
    // b fastest in linear block id -> t-adjacent blocks (delta id = 64 == 0 mod 8)
    // land on the same XCD, sharing the 64B x/out lines in that XCD's L2.
    gcn_mfma<<<dim3(B_, T_ / GT), 256, 0, stream>>>(x, dist, wf, bias, gam, bet, out);
}